// Round 17
// baseline (344.698 us; speedup 1.0000x reference)
//
#include <hip/hip_runtime.h>
#include <math.h>

#define NPTS  16384
#define G     32              // grid cells per axis
#define NC    (G * G * G)     // 32768 cells per set
#define CW    0.25f           // cell width: domain [-4,4]
#define ICW   4.0f            // 1/CW
#define TOTP  65536           // 4 sets x 16384 points
#define TOTQ  32768           // mean denominator: B*N per direction

// set id: cloud*2 + batch. query set z (0..3) -> ref set z^2 (other cloud, same batch)

__device__ __forceinline__ int cellof(float x) {
    int c = (int)floorf((x + 4.0f) * ICW);
    return min(max(c, 0), G - 1);
}

// decode point, write packed float4, cell id, histogram  (validated r16)
__global__ __launch_bounds__(256) void hist_kernel(const float* __restrict__ pred,
                                                   const float* __restrict__ target,
                                                   float4* __restrict__ pts,
                                                   int* __restrict__ cellids,
                                                   int* __restrict__ hist) {
    int t = blockIdx.x * 256 + threadIdx.x;      // 0..65535
    int cloud = t >> 15, w = t & 32767, b = w >> 14, i = w & 16383;
    const float* src = cloud ? target : pred;
    float x = src[(b * NPTS + i) * 3 + 0];
    float y = src[(b * NPTS + i) * 3 + 1];
    float z = src[(b * NPTS + i) * 3 + 2];
    int set = cloud * 2 + b;
    int c = (cellof(z) * G + cellof(y)) * G + cellof(x);
    int u = (set << 14) + i;
    pts[u] = make_float4(x, y, z, __int_as_float(i));
    cellids[u] = c;
    atomicAdd(&hist[(set << 15) + c], 1);
}

// per-set exclusive scan -> cs (CSR starts, +1 sentinel) and next  (validated r16)
__global__ __launch_bounds__(1024) void scan_kernel(const int* __restrict__ hist,
                                                    int* __restrict__ cs,
                                                    int* __restrict__ next) {
    __shared__ int tsum[1024];
    const int s = blockIdx.x;            // set 0..3
    const int tid = threadIdx.x;
    int v[32]; int sum = 0;
    const int base = (s << 15) + tid * 32;
    #pragma unroll
    for (int r = 0; r < 32; ++r) { v[r] = hist[base + r]; sum += v[r]; }
    tsum[tid] = sum;
    __syncthreads();
    for (int off = 1; off < 1024; off <<= 1) {
        int x = (tid >= off) ? tsum[tid - off] : 0;
        __syncthreads();
        tsum[tid] += x;
        __syncthreads();
    }
    int run = (tid > 0) ? tsum[tid - 1] : 0;
    const int cbase = s * (NC + 1) + tid * 32;
    #pragma unroll
    for (int r = 0; r < 32; ++r) {
        cs[cbase + r] = run;
        next[base + r] = run;
        run += v[r];
    }
    if (tid == 1023) cs[s * (NC + 1) + NC] = run;   // = 16384
}

__global__ __launch_bounds__(256) void scatter_kernel(const float4* __restrict__ pts,
                                                      const int* __restrict__ cellids,
                                                      int* __restrict__ next,
                                                      float4* __restrict__ sorted) {
    int u = blockIdx.x * 256 + threadIdx.x;      // 0..65535
    int set = u >> 14;
    int c = cellids[u];
    int idx = atomicAdd(&next[(set << 15) + c], 1);
    sorted[(set << 14) + idx] = pts[u];
}

#define EVAL(j) { float4 p = sr[j];                                   \
    float dx = q.x - p.x, dy = q.y - p.y, dz = q.z - p.z;             \
    md2 = fminf(md2, fmaf(dx, dx, fmaf(dy, dy, dz * dz))); }

// Bulk pass: 4 lanes per query, k=1 box (3x3x3 cells = 9 contiguous CSR runs).
// g >= CW on every non-edge side after the k=1 box -> most queries terminate.
__global__ __launch_bounds__(256) void nnA_kernel(const float4* __restrict__ sorted,
                                                  const int* __restrict__ cs,
                                                  float* __restrict__ dout,
                                                  int* __restrict__ tailcnt,
                                                  int* __restrict__ taillist) {
    const int gthr = blockIdx.x * 256 + threadIdx.x;  // 0..262143
    const int quad = gthr >> 2;                       // query id: (z<<14)+qi
    const int lane4 = gthr & 3;
    const int z = quad >> 14;
    float4 q = sorted[quad];                          // broadcast within quad
    const float4* __restrict__ sr = sorted + ((z ^ 2) << 14);
    const int* __restrict__ csr = cs + (z ^ 2) * (NC + 1);

    const int cx = cellof(q.x), cy = cellof(q.y), cz = cellof(q.z);
    const int xlo = max(cx - 1, 0), xhi = min(cx + 1, G - 1);
    float md2 = __builtin_inff();

    #pragma unroll
    for (int dz = -1; dz <= 1; ++dz) {
        const int zz = cz + dz;
        if ((unsigned)zz >= G) continue;
        #pragma unroll
        for (int dy = -1; dy <= 1; ++dy) {
            const int yy = cy + dy;
            if ((unsigned)yy >= G) continue;
            const int rowbase = (zz * G + yy) * G;
            const int s0 = csr[rowbase + xlo], s1 = csr[rowbase + xhi + 1];
            int j = s0 + lane4;
            for (; j + 4 < s1; j += 8) { EVAL(j) EVAL(j + 4) }
            if (j < s1) EVAL(j)
        }
    }
    // quad reduction
    md2 = fminf(md2, __shfl_xor(md2, 1));
    md2 = fminf(md2, __shfl_xor(md2, 2));

    if (lane4 == 0) {
        // exact gap to unsearched space after the k=1 box (inf at domain edges)
        float g = __builtin_inff();
        if (cx - 1 > 0)     g = fminf(g, q.x - ((cx - 1) * CW - 4.0f));
        if (cx + 1 < G - 1) g = fminf(g, ((cx + 2) * CW - 4.0f) - q.x);
        if (cy - 1 > 0)     g = fminf(g, q.y - ((cy - 1) * CW - 4.0f));
        if (cy + 1 < G - 1) g = fminf(g, ((cy + 2) * CW - 4.0f) - q.y);
        if (cz - 1 > 0)     g = fminf(g, q.z - ((cz - 1) * CW - 4.0f));
        if (cz + 1 < G - 1) g = fminf(g, ((cz + 2) * CW - 4.0f) - q.z);
        if (md2 <= g * g) {
            dout[quad] = sqrtf(md2);
        } else {
            int idx = atomicAdd(tailcnt, 1);
            taillist[idx] = quad;     // dout[quad] written by tail kernel
        }
    }
}

// Tail: full expanding shell walk (r16-validated logic) for the few failures.
__global__ __launch_bounds__(256) void tail_kernel(const float4* __restrict__ sorted,
                                                   const int* __restrict__ cs,
                                                   const int* __restrict__ tailcnt,
                                                   const int* __restrict__ taillist,
                                                   float* __restrict__ dout) {
    const int cnt = *tailcnt;
    for (int t = blockIdx.x * 256 + threadIdx.x; t < cnt; t += 16 * 256) {
        const int quad = taillist[t];
        const int z = quad >> 14;
        float4 q = sorted[quad];
        const float4* __restrict__ sr = sorted + ((z ^ 2) << 14);
        const int* __restrict__ csr = cs + (z ^ 2) * (NC + 1);
        const int cx = cellof(q.x), cy = cellof(q.y), cz = cellof(q.z);
        float md2 = __builtin_inff();
        for (int k = 0; k < G; ++k) {
            const int zlo = max(cz - k, 0), zhi = min(cz + k, G - 1);
            const int ylo = max(cy - k, 0), yhi = min(cy + k, G - 1);
            const int xlo = max(cx - k, 0), xhi = min(cx + k, G - 1);
            for (int zz = zlo; zz <= zhi; ++zz) {
                const bool zf = (zz == cz - k) || (zz == cz + k);
                for (int yy = ylo; yy <= yhi; ++yy) {
                    const int rowbase = (zz * G + yy) * G;
                    if (zf || (yy == cy - k) || (yy == cy + k)) {
                        const int s0 = csr[rowbase + xlo], s1 = csr[rowbase + xhi + 1];
                        for (int j = s0; j < s1; ++j) EVAL(j)
                    } else {
                        const int xa = cx - k, xb = cx + k;
                        if (xa >= 0) {
                            const int s0 = csr[rowbase + xa], s1 = csr[rowbase + xa + 1];
                            for (int j = s0; j < s1; ++j) EVAL(j)
                        }
                        if (xb <= G - 1) {
                            const int s0 = csr[rowbase + xb], s1 = csr[rowbase + xb + 1];
                            for (int j = s0; j < s1; ++j) EVAL(j)
                        }
                    }
                }
            }
            float g = __builtin_inff();
            if (cx - k > 0)     g = fminf(g, q.x - ((cx - k) * CW - 4.0f));
            if (cx + k < G - 1) g = fminf(g, ((cx + k + 1) * CW - 4.0f) - q.x);
            if (cy - k > 0)     g = fminf(g, q.y - ((cy - k) * CW - 4.0f));
            if (cy + k < G - 1) g = fminf(g, ((cy + k + 1) * CW - 4.0f) - q.y);
            if (cz - k > 0)     g = fminf(g, q.z - ((cz - k) * CW - 4.0f));
            if (cz + k < G - 1) g = fminf(g, ((cz + k + 1) * CW - 4.0f) - q.z);
            if (md2 <= g * g) break;
        }
        dout[quad] = sqrtf(md2);
    }
}
#undef EVAL

// single-block final reduce: fixed order -> deterministic
__global__ __launch_bounds__(1024) void reduce_kernel(const float* __restrict__ dout,
                                                      float* __restrict__ out) {
    float s = 0.f;
    #pragma unroll
    for (int k = 0; k < 64; ++k)
        s += dout[k * 1024 + threadIdx.x];
    #pragma unroll
    for (int off = 32; off; off >>= 1) s += __shfl_down(s, off);
    __shared__ float wsum[16];
    int lane = threadIdx.x & 63, wv = threadIdx.x >> 6;
    if (lane == 0) wsum[wv] = s;
    __syncthreads();
    if (threadIdx.x == 0) {
        float tt = 0.f;
        #pragma unroll
        for (int i = 0; i < 16; ++i) tt += wsum[i];
        out[0] = tt / (float)TOTQ;
    }
}

extern "C" void kernel_launch(void* const* d_in, const int* in_sizes, int n_in,
                              void* d_out, int out_size, void* d_ws, size_t ws_size,
                              hipStream_t stream) {
    const float* pred   = (const float*)d_in[0];
    const float* target = (const float*)d_in[1];
    char* ws = (char*)d_ws;

    float4* pts      = (float4*)(ws);                                   // 1 MiB
    float4* sorted   = (float4*)(ws + (size_t)1024 * 1024);             // 1 MiB
    int*    cellids  = (int*)  (ws + (size_t)2048 * 1024);              // 256 KiB
    int*    hist     = (int*)  (ws + (size_t)2304 * 1024);              // 512 KiB
    int*    tailcnt  = (int*)  (ws + (size_t)2816 * 1024);              // 4 B (zeroed w/ hist)
    int*    next     = (int*)  (ws + (size_t)2848 * 1024);              // 512 KiB
    int*    cs       = (int*)  (ws + (size_t)3360 * 1024);              // ~512 KiB
    int*    taillist = (int*)  (ws + (size_t)3904 * 1024);              // 256 KiB
    float*  dout     = (float*)(ws + (size_t)4160 * 1024);              // 256 KiB
    float*  out      = (float*)d_out;

    hipMemsetAsync(hist, 0, 513 * 1024, stream);   // hist + tailcnt in one call

    hist_kernel<<<TOTP / 256, 256, 0, stream>>>(pred, target, pts, cellids, hist);
    scan_kernel<<<4, 1024, 0, stream>>>(hist, cs, next);
    scatter_kernel<<<TOTP / 256, 256, 0, stream>>>(pts, cellids, next, sorted);

    nnA_kernel<<<TOTP * 4 / 256, 256, 0, stream>>>(sorted, cs, dout, tailcnt, taillist);
    tail_kernel<<<16, 256, 0, stream>>>(sorted, cs, tailcnt, taillist, dout);

    reduce_kernel<<<1, 1024, 0, stream>>>(dout, out);
}

// Round 18
// 92.121 us; speedup vs baseline: 3.7418x; 3.7418x over previous
//
#include <hip/hip_runtime.h>
#include <math.h>

#define NPTS  16384
#define G     32              // grid cells per axis
#define NC    (G * G * G)     // 32768 cells per set
#define CW    0.25f           // cell width: domain [-4,4]
#define ICW   4.0f            // 1/CW
#define TOTP  65536           // 4 sets x 16384 points
#define TOTQ  32768           // mean denominator: B*N per direction

// set id: cloud*2 + batch. query set z (0..3) -> ref set z^2 (other cloud, same batch)

__device__ __forceinline__ int cellof(float x) {
    int c = (int)floorf((x + 4.0f) * ICW);
    return min(max(c, 0), G - 1);
}

// decode point, write packed float4, cell id, histogram  (validated r16/r17)
__global__ __launch_bounds__(256) void hist_kernel(const float* __restrict__ pred,
                                                   const float* __restrict__ target,
                                                   float4* __restrict__ pts,
                                                   int* __restrict__ cellids,
                                                   int* __restrict__ hist) {
    int t = blockIdx.x * 256 + threadIdx.x;      // 0..65535
    int cloud = t >> 15, w = t & 32767, b = w >> 14, i = w & 16383;
    const float* src = cloud ? target : pred;
    float x = src[(b * NPTS + i) * 3 + 0];
    float y = src[(b * NPTS + i) * 3 + 1];
    float z = src[(b * NPTS + i) * 3 + 2];
    int set = cloud * 2 + b;
    int c = (cellof(z) * G + cellof(y)) * G + cellof(x);
    int u = (set << 14) + i;
    pts[u] = make_float4(x, y, z, __int_as_float(i));
    cellids[u] = c;
    atomicAdd(&hist[(set << 15) + c], 1);
}

// per-set exclusive scan -> cs (CSR starts, +1 sentinel) and next  (validated)
__global__ __launch_bounds__(1024) void scan_kernel(const int* __restrict__ hist,
                                                    int* __restrict__ cs,
                                                    int* __restrict__ next) {
    __shared__ int tsum[1024];
    const int s = blockIdx.x;            // set 0..3
    const int tid = threadIdx.x;
    int v[32]; int sum = 0;
    const int base = (s << 15) + tid * 32;
    #pragma unroll
    for (int r = 0; r < 32; ++r) { v[r] = hist[base + r]; sum += v[r]; }
    tsum[tid] = sum;
    __syncthreads();
    for (int off = 1; off < 1024; off <<= 1) {
        int x = (tid >= off) ? tsum[tid - off] : 0;
        __syncthreads();
        tsum[tid] += x;
        __syncthreads();
    }
    int run = (tid > 0) ? tsum[tid - 1] : 0;
    const int cbase = s * (NC + 1) + tid * 32;
    #pragma unroll
    for (int r = 0; r < 32; ++r) {
        cs[cbase + r] = run;
        next[base + r] = run;
        run += v[r];
    }
    if (tid == 1023) cs[s * (NC + 1) + NC] = run;   // = 16384
}

__global__ __launch_bounds__(256) void scatter_kernel(const float4* __restrict__ pts,
                                                      const int* __restrict__ cellids,
                                                      int* __restrict__ next,
                                                      float4* __restrict__ sorted) {
    int u = blockIdx.x * 256 + threadIdx.x;      // 0..65535
    int set = u >> 14;
    int c = cellids[u];
    int idx = atomicAdd(&next[(set << 15) + c], 1);
    sorted[(set << 14) + idx] = pts[u];
}

#define EVAL(j) { float4 p = sr[j];                                   \
    float dx = q.x - p.x, dy = q.y - p.y, dz = q.z - p.z;             \
    md2 = fminf(md2, fmaf(dx, dx, fmaf(dy, dy, dz * dz))); }

// Bulk pass: 4 lanes per query, k=1 box. All 18 CSR range loads hoisted &
// fully unrolled (registers, independent issue) before the eval loops.
__global__ __launch_bounds__(256) void nnA_kernel(const float4* __restrict__ sorted,
                                                  const int* __restrict__ cs,
                                                  float* __restrict__ dout,
                                                  int* __restrict__ tailcnt,
                                                  int* __restrict__ taillist) {
    const int gthr = blockIdx.x * 256 + threadIdx.x;  // 0..262143
    const int quad = gthr >> 2;                       // query id: (z<<14)+qi
    const int lane4 = gthr & 3;
    const int z = quad >> 14;
    float4 q = sorted[quad];
    const float4* __restrict__ sr = sorted + ((z ^ 2) << 14);
    const int* __restrict__ csr = cs + (z ^ 2) * (NC + 1);

    const int cx = cellof(q.x), cy = cellof(q.y), cz = cellof(q.z);
    const int xlo = max(cx - 1, 0), xhi = min(cx + 1, G - 1);

    int s0a[9], s1a[9];
    #pragma unroll
    for (int i = 0; i < 9; ++i) {
        const int zz = cz + (i / 3) - 1;
        const int yy = cy + (i % 3) - 1;
        const bool ok = ((unsigned)zz < G) && ((unsigned)yy < G);
        const int rowbase = (zz * G + yy) * G;
        s0a[i] = ok ? csr[rowbase + xlo] : 0;
        s1a[i] = ok ? csr[rowbase + xhi + 1] : 0;
    }

    float md2 = __builtin_inff();
    #pragma unroll
    for (int i = 0; i < 9; ++i)
        for (int j = s0a[i] + lane4; j < s1a[i]; j += 4) EVAL(j)

    md2 = fminf(md2, __shfl_xor(md2, 1));
    md2 = fminf(md2, __shfl_xor(md2, 2));

    if (lane4 == 0) {
        float g = __builtin_inff();
        if (cx - 1 > 0)     g = fminf(g, q.x - ((cx - 1) * CW - 4.0f));
        if (cx + 1 < G - 1) g = fminf(g, ((cx + 2) * CW - 4.0f) - q.x);
        if (cy - 1 > 0)     g = fminf(g, q.y - ((cy - 1) * CW - 4.0f));
        if (cy + 1 < G - 1) g = fminf(g, ((cy + 2) * CW - 4.0f) - q.y);
        if (cz - 1 > 0)     g = fminf(g, q.z - ((cz - 1) * CW - 4.0f));
        if (cz + 1 < G - 1) g = fminf(g, ((cz + 2) * CW - 4.0f) - q.z);
        if (md2 <= g * g) {
            dout[quad] = sqrtf(md2);
        } else {
            int idx = atomicAdd(tailcnt, 1);
            taillist[idx] = quad;     // dout[quad] written by tail kernel
        }
    }
}

// Tail: ONE WAVE per query. Shell k = flat list of R(k) contiguous CSR runs,
// lane-parallel; butterfly-reduce md2; wave-uniform exact termination.
// Run decomposition (== r16's validated cell coverage):
//   type A: zz = cz+-k,          yy in [cy-k,cy+k],   full x-run [cx-k,cx+k]
//   type B: zz interior,         yy = cy+-k,          full x-run
//   type C: zz interior, yy interior, single cells x = cx+-k
__global__ __launch_bounds__(256) void tail_kernel(const float4* __restrict__ sorted,
                                                   const int* __restrict__ cs,
                                                   const int* __restrict__ tailcnt,
                                                   const int* __restrict__ taillist,
                                                   float* __restrict__ dout) {
    const int cnt = *tailcnt;
    const int wid = blockIdx.x * 4 + (threadIdx.x >> 6);
    const int ln = threadIdx.x & 63;
    const int nw = gridDim.x * 4;

    for (int t = wid; t < cnt; t += nw) {
        const int quad = taillist[t];
        const int z = quad >> 14;
        float4 q = sorted[quad];
        const float4* __restrict__ sr = sorted + ((z ^ 2) << 14);
        const int* __restrict__ csr = cs + (z ^ 2) * (NC + 1);
        const int cx = cellof(q.x), cy = cellof(q.y), cz = cellof(q.z);

        float md2 = __builtin_inff();

        // k = 0: home cell, lane-strided points
        {
            const int rowbase = (cz * G + cy) * G;
            const int s0 = csr[rowbase + cx], s1 = csr[rowbase + cx + 1];
            for (int j = s0 + ln; j < s1; j += 64) EVAL(j)
        }

        for (int k = 1; k < G; ++k) {
            // reduce md2 across wave; exact termination for the (k-1)-box
            #pragma unroll
            for (int off = 1; off < 64; off <<= 1)
                md2 = fminf(md2, __shfl_xor(md2, off));
            const int km = k - 1;
            float g = __builtin_inff();
            if (cx - km > 0)     g = fminf(g, q.x - ((cx - km) * CW - 4.0f));
            if (cx + km < G - 1) g = fminf(g, ((cx + km + 1) * CW - 4.0f) - q.x);
            if (cy - km > 0)     g = fminf(g, q.y - ((cy - km) * CW - 4.0f));
            if (cy + km < G - 1) g = fminf(g, ((cy + km + 1) * CW - 4.0f) - q.y);
            if (cz - km > 0)     g = fminf(g, q.z - ((cz - km) * CW - 4.0f));
            if (cz + km < G - 1) g = fminf(g, ((cz + km + 1) * CW - 4.0f) - q.z);
            if (md2 <= g * g) break;

            const int W = 2 * k + 1, Wm = 2 * k - 1;
            const int A = 2 * W, Bc = 2 * Wm;
            const int R = A + Bc + 2 * Wm * Wm;
            for (int m = ln; m < R; m += 64) {
                int zz, yy, xlo, xhi;
                if (m < A) {                     // type A: z-faces
                    zz = cz + ((m < W) ? -k : k);
                    yy = cy + ((m < W) ? m : m - W) - k;
                    if ((unsigned)zz >= G || (unsigned)yy >= G) continue;
                    xlo = max(cx - k, 0); xhi = min(cx + k, G - 1);
                } else if (m < A + Bc) {         // type B: y-edge rows
                    const int t2 = m - A;
                    zz = cz + ((t2 < Wm) ? t2 : t2 - Wm) - (k - 1);
                    yy = cy + ((t2 < Wm) ? -k : k);
                    if ((unsigned)zz >= G || (unsigned)yy >= G) continue;
                    xlo = max(cx - k, 0); xhi = min(cx + k, G - 1);
                } else {                          // type C: single cells x=cx+-k
                    int t2 = m - A - Bc;
                    const int side = t2 & 1; t2 >>= 1;
                    zz = cz + t2 / Wm - (k - 1);
                    yy = cy + t2 % Wm - (k - 1);
                    const int xx = cx + (side ? k : -k);
                    if ((unsigned)zz >= G || (unsigned)yy >= G || (unsigned)xx >= G) continue;
                    xlo = xx; xhi = xx;
                }
                const int rowbase = (zz * G + yy) * G;
                const int s0 = csr[rowbase + xlo], s1 = csr[rowbase + xhi + 1];
                for (int j = s0; j < s1; ++j) EVAL(j)
            }
        }

        // final reduce (idempotent if already reduced before break)
        #pragma unroll
        for (int off = 1; off < 64; off <<= 1)
            md2 = fminf(md2, __shfl_xor(md2, off));
        if (ln == 0) dout[quad] = sqrtf(md2);
    }
}
#undef EVAL

// single-block final reduce: fixed order -> deterministic
__global__ __launch_bounds__(1024) void reduce_kernel(const float* __restrict__ dout,
                                                      float* __restrict__ out) {
    float s = 0.f;
    #pragma unroll
    for (int k = 0; k < 64; ++k)
        s += dout[k * 1024 + threadIdx.x];
    #pragma unroll
    for (int off = 32; off; off >>= 1) s += __shfl_down(s, off);
    __shared__ float wsum[16];
    int lane = threadIdx.x & 63, wv = threadIdx.x >> 6;
    if (lane == 0) wsum[wv] = s;
    __syncthreads();
    if (threadIdx.x == 0) {
        float tt = 0.f;
        #pragma unroll
        for (int i = 0; i < 16; ++i) tt += wsum[i];
        out[0] = tt / (float)TOTQ;
    }
}

extern "C" void kernel_launch(void* const* d_in, const int* in_sizes, int n_in,
                              void* d_out, int out_size, void* d_ws, size_t ws_size,
                              hipStream_t stream) {
    const float* pred   = (const float*)d_in[0];
    const float* target = (const float*)d_in[1];
    char* ws = (char*)d_ws;

    float4* pts      = (float4*)(ws);                                   // 1 MiB
    float4* sorted   = (float4*)(ws + (size_t)1024 * 1024);             // 1 MiB
    int*    cellids  = (int*)  (ws + (size_t)2048 * 1024);              // 256 KiB
    int*    hist     = (int*)  (ws + (size_t)2304 * 1024);              // 512 KiB
    int*    tailcnt  = (int*)  (ws + (size_t)2816 * 1024);              // 4 B (zeroed w/ hist)
    int*    next     = (int*)  (ws + (size_t)2848 * 1024);              // 512 KiB
    int*    cs       = (int*)  (ws + (size_t)3360 * 1024);              // ~512 KiB
    int*    taillist = (int*)  (ws + (size_t)3904 * 1024);              // 256 KiB
    float*  dout     = (float*)(ws + (size_t)4160 * 1024);              // 256 KiB
    float*  out      = (float*)d_out;

    hipMemsetAsync(hist, 0, 513 * 1024, stream);   // hist + tailcnt in one call

    hist_kernel<<<TOTP / 256, 256, 0, stream>>>(pred, target, pts, cellids, hist);
    scan_kernel<<<4, 1024, 0, stream>>>(hist, cs, next);
    scatter_kernel<<<TOTP / 256, 256, 0, stream>>>(pts, cellids, next, sorted);

    nnA_kernel<<<TOTP * 4 / 256, 256, 0, stream>>>(sorted, cs, dout, tailcnt, taillist);
    tail_kernel<<<512, 256, 0, stream>>>(sorted, cs, tailcnt, taillist, dout);

    reduce_kernel<<<1, 1024, 0, stream>>>(dout, out);
}

// Round 19
// 77.100 us; speedup vs baseline: 4.4708x; 1.1948x over previous
//
#include <hip/hip_runtime.h>
#include <math.h>

#define NPTS  16384
#define G     32              // grid cells per axis
#define NC    (G * G * G)     // 32768 cells per set
#define CW    0.25f           // cell width: domain [-4,4]
#define ICW   4.0f            // 1/CW
#define TOTP  65536           // 4 sets x 16384 points
#define TOTQ  32768           // mean denominator: B*N per direction

// set id: cloud*2 + batch. query set z (0..3) -> ref set z^2 (other cloud, same batch)

__device__ __forceinline__ int cellof(float x) {
    int c = (int)floorf((x + 4.0f) * ICW);
    return min(max(c, 0), G - 1);
}

// zero hist (131072 ints) + tailcnt (1 int, contiguous after hist)
__global__ __launch_bounds__(256) void zero_kernel(int* __restrict__ hist) {
    int gid = blockIdx.x * 256 + threadIdx.x;     // 0..32767
    ((int4*)hist)[gid] = make_int4(0, 0, 0, 0);
    if (gid == 0) hist[NC * 4] = 0;               // tailcnt
}

// decode point, write packed float4, cell id, histogram  (validated r16/r17)
__global__ __launch_bounds__(256) void hist_kernel(const float* __restrict__ pred,
                                                   const float* __restrict__ target,
                                                   float4* __restrict__ pts,
                                                   int* __restrict__ cellids,
                                                   int* __restrict__ hist) {
    int t = blockIdx.x * 256 + threadIdx.x;      // 0..65535
    int cloud = t >> 15, w = t & 32767, b = w >> 14, i = w & 16383;
    const float* src = cloud ? target : pred;
    float x = src[(b * NPTS + i) * 3 + 0];
    float y = src[(b * NPTS + i) * 3 + 1];
    float z = src[(b * NPTS + i) * 3 + 2];
    int set = cloud * 2 + b;
    int c = (cellof(z) * G + cellof(y)) * G + cellof(x);
    int u = (set << 14) + i;
    pts[u] = make_float4(x, y, z, __int_as_float(i));
    cellids[u] = c;
    atomicAdd(&hist[(set << 15) + c], 1);
}

// per-set exclusive scan -> cs (CSR starts, +1 sentinel) and next  (validated)
__global__ __launch_bounds__(1024) void scan_kernel(const int* __restrict__ hist,
                                                    int* __restrict__ cs,
                                                    int* __restrict__ next) {
    __shared__ int tsum[1024];
    const int s = blockIdx.x;            // set 0..3
    const int tid = threadIdx.x;
    int v[32]; int sum = 0;
    const int base = (s << 15) + tid * 32;
    #pragma unroll
    for (int r = 0; r < 32; ++r) { v[r] = hist[base + r]; sum += v[r]; }
    tsum[tid] = sum;
    __syncthreads();
    for (int off = 1; off < 1024; off <<= 1) {
        int x = (tid >= off) ? tsum[tid - off] : 0;
        __syncthreads();
        tsum[tid] += x;
        __syncthreads();
    }
    int run = (tid > 0) ? tsum[tid - 1] : 0;
    const int cbase = s * (NC + 1) + tid * 32;
    #pragma unroll
    for (int r = 0; r < 32; ++r) {
        cs[cbase + r] = run;
        next[base + r] = run;
        run += v[r];
    }
    if (tid == 1023) cs[s * (NC + 1) + NC] = run;   // = 16384
}

__global__ __launch_bounds__(256) void scatter_kernel(const float4* __restrict__ pts,
                                                      const int* __restrict__ cellids,
                                                      int* __restrict__ next,
                                                      float4* __restrict__ sorted) {
    int u = blockIdx.x * 256 + threadIdx.x;      // 0..65535
    int set = u >> 14;
    int c = cellids[u];
    int idx = atomicAdd(&next[(set << 15) + c], 1);
    sorted[(set << 14) + idx] = pts[u];
}

#define EVAL(j) { float4 p = sr[j];                                   \
    float dx = q.x - p.x, dy = q.y - p.y, dz = q.z - p.z;             \
    md2 = fminf(md2, fmaf(dx, dx, fmaf(dy, dy, dz * dz))); }

// Bulk pass: 4 lanes per query, k=1 box, 18 CSR loads hoisted (validated r18)
__global__ __launch_bounds__(256) void nnA_kernel(const float4* __restrict__ sorted,
                                                  const int* __restrict__ cs,
                                                  float* __restrict__ dout,
                                                  int* __restrict__ tailcnt,
                                                  int* __restrict__ taillist) {
    const int gthr = blockIdx.x * 256 + threadIdx.x;  // 0..262143
    const int quad = gthr >> 2;                       // query id: (z<<14)+qi
    const int lane4 = gthr & 3;
    const int z = quad >> 14;
    float4 q = sorted[quad];
    const float4* __restrict__ sr = sorted + ((z ^ 2) << 14);
    const int* __restrict__ csr = cs + (z ^ 2) * (NC + 1);

    const int cx = cellof(q.x), cy = cellof(q.y), cz = cellof(q.z);
    const int xlo = max(cx - 1, 0), xhi = min(cx + 1, G - 1);

    int s0a[9], s1a[9];
    #pragma unroll
    for (int i = 0; i < 9; ++i) {
        const int zz = cz + (i / 3) - 1;
        const int yy = cy + (i % 3) - 1;
        const bool ok = ((unsigned)zz < G) && ((unsigned)yy < G);
        const int rowbase = (zz * G + yy) * G;
        s0a[i] = ok ? csr[rowbase + xlo] : 0;
        s1a[i] = ok ? csr[rowbase + xhi + 1] : 0;
    }

    float md2 = __builtin_inff();
    #pragma unroll
    for (int i = 0; i < 9; ++i)
        for (int j = s0a[i] + lane4; j < s1a[i]; j += 4) EVAL(j)

    md2 = fminf(md2, __shfl_xor(md2, 1));
    md2 = fminf(md2, __shfl_xor(md2, 2));

    if (lane4 == 0) {
        float g = __builtin_inff();
        if (cx - 1 > 0)     g = fminf(g, q.x - ((cx - 1) * CW - 4.0f));
        if (cx + 1 < G - 1) g = fminf(g, ((cx + 2) * CW - 4.0f) - q.x);
        if (cy - 1 > 0)     g = fminf(g, q.y - ((cy - 1) * CW - 4.0f));
        if (cy + 1 < G - 1) g = fminf(g, ((cy + 2) * CW - 4.0f) - q.y);
        if (cz - 1 > 0)     g = fminf(g, q.z - ((cz - 1) * CW - 4.0f));
        if (cz + 1 < G - 1) g = fminf(g, ((cz + 2) * CW - 4.0f) - q.z);
        if (md2 <= g * g) {
            dout[quad] = sqrtf(md2);
        } else {
            int idx = atomicAdd(tailcnt, 1);
            taillist[idx] = quad;     // dout[quad] written by tail kernel
        }
    }
}

// Tail: ONE WAVE per query, lane-parallel shell runs (validated r18)
__global__ __launch_bounds__(256) void tail_kernel(const float4* __restrict__ sorted,
                                                   const int* __restrict__ cs,
                                                   const int* __restrict__ tailcnt,
                                                   const int* __restrict__ taillist,
                                                   float* __restrict__ dout) {
    const int cnt = *tailcnt;
    const int wid = blockIdx.x * 4 + (threadIdx.x >> 6);
    const int ln = threadIdx.x & 63;
    const int nw = gridDim.x * 4;

    for (int t = wid; t < cnt; t += nw) {
        const int quad = taillist[t];
        const int z = quad >> 14;
        float4 q = sorted[quad];
        const float4* __restrict__ sr = sorted + ((z ^ 2) << 14);
        const int* __restrict__ csr = cs + (z ^ 2) * (NC + 1);
        const int cx = cellof(q.x), cy = cellof(q.y), cz = cellof(q.z);

        float md2 = __builtin_inff();

        {
            const int rowbase = (cz * G + cy) * G;
            const int s0 = csr[rowbase + cx], s1 = csr[rowbase + cx + 1];
            for (int j = s0 + ln; j < s1; j += 64) EVAL(j)
        }

        for (int k = 1; k < G; ++k) {
            #pragma unroll
            for (int off = 1; off < 64; off <<= 1)
                md2 = fminf(md2, __shfl_xor(md2, off));
            const int km = k - 1;
            float g = __builtin_inff();
            if (cx - km > 0)     g = fminf(g, q.x - ((cx - km) * CW - 4.0f));
            if (cx + km < G - 1) g = fminf(g, ((cx + km + 1) * CW - 4.0f) - q.x);
            if (cy - km > 0)     g = fminf(g, q.y - ((cy - km) * CW - 4.0f));
            if (cy + km < G - 1) g = fminf(g, ((cy + km + 1) * CW - 4.0f) - q.y);
            if (cz - km > 0)     g = fminf(g, q.z - ((cz - km) * CW - 4.0f));
            if (cz + km < G - 1) g = fminf(g, ((cz + km + 1) * CW - 4.0f) - q.z);
            if (md2 <= g * g) break;

            const int W = 2 * k + 1, Wm = 2 * k - 1;
            const int A = 2 * W, Bc = 2 * Wm;
            const int R = A + Bc + 2 * Wm * Wm;
            for (int m = ln; m < R; m += 64) {
                int zz, yy, xlo, xhi;
                if (m < A) {
                    zz = cz + ((m < W) ? -k : k);
                    yy = cy + ((m < W) ? m : m - W) - k;
                    if ((unsigned)zz >= G || (unsigned)yy >= G) continue;
                    xlo = max(cx - k, 0); xhi = min(cx + k, G - 1);
                } else if (m < A + Bc) {
                    const int t2 = m - A;
                    zz = cz + ((t2 < Wm) ? t2 : t2 - Wm) - (k - 1);
                    yy = cy + ((t2 < Wm) ? -k : k);
                    if ((unsigned)zz >= G || (unsigned)yy >= G) continue;
                    xlo = max(cx - k, 0); xhi = min(cx + k, G - 1);
                } else {
                    int t2 = m - A - Bc;
                    const int side = t2 & 1; t2 >>= 1;
                    zz = cz + t2 / Wm - (k - 1);
                    yy = cy + t2 % Wm - (k - 1);
                    const int xx = cx + (side ? k : -k);
                    if ((unsigned)zz >= G || (unsigned)yy >= G || (unsigned)xx >= G) continue;
                    xlo = xx; xhi = xx;
                }
                const int rowbase = (zz * G + yy) * G;
                const int s0 = csr[rowbase + xlo], s1 = csr[rowbase + xhi + 1];
                for (int j = s0; j < s1; ++j) EVAL(j)
            }
        }

        #pragma unroll
        for (int off = 1; off < 64; off <<= 1)
            md2 = fminf(md2, __shfl_xor(md2, off));
        if (ln == 0) dout[quad] = sqrtf(md2);
    }
}
#undef EVAL

// Stage A: 64 blocks x 1024 sums -> partials (deterministic fixed order)
__global__ __launch_bounds__(256) void reduceA_kernel(const float* __restrict__ dout,
                                                      float* __restrict__ partials) {
    int base = blockIdx.x * 1024;
    float s = 0.f;
    #pragma unroll
    for (int k = 0; k < 4; ++k)
        s += dout[base + k * 256 + threadIdx.x];
    #pragma unroll
    for (int off = 32; off; off >>= 1) s += __shfl_down(s, off);
    __shared__ float wsum[4];
    int lane = threadIdx.x & 63, wv = threadIdx.x >> 6;
    if (lane == 0) wsum[wv] = s;
    __syncthreads();
    if (threadIdx.x == 0) partials[blockIdx.x] = wsum[0] + wsum[1] + wsum[2] + wsum[3];
}

__global__ void reduceB_kernel(const float* __restrict__ partials, float* __restrict__ out) {
    float s = partials[threadIdx.x];
    #pragma unroll
    for (int off = 32; off; off >>= 1) s += __shfl_down(s, off);
    if (threadIdx.x == 0) out[0] = s / (float)TOTQ;
}

extern "C" void kernel_launch(void* const* d_in, const int* in_sizes, int n_in,
                              void* d_out, int out_size, void* d_ws, size_t ws_size,
                              hipStream_t stream) {
    const float* pred   = (const float*)d_in[0];
    const float* target = (const float*)d_in[1];
    char* ws = (char*)d_ws;

    float4* pts      = (float4*)(ws);                                   // 1 MiB
    float4* sorted   = (float4*)(ws + (size_t)1024 * 1024);             // 1 MiB
    int*    cellids  = (int*)  (ws + (size_t)2048 * 1024);              // 256 KiB
    int*    hist     = (int*)  (ws + (size_t)2304 * 1024);              // 512 KiB
    int*    tailcnt  = (int*)  (ws + (size_t)2816 * 1024);              // 4 B (contiguous after hist)
    int*    next     = (int*)  (ws + (size_t)2848 * 1024);              // 512 KiB
    int*    cs       = (int*)  (ws + (size_t)3360 * 1024);              // ~513 KiB
    int*    taillist = (int*)  (ws + (size_t)3904 * 1024);              // 256 KiB
    float*  dout     = (float*)(ws + (size_t)4160 * 1024);              // 256 KiB
    float*  partials = (float*)(ws + (size_t)4416 * 1024);              // 256 B
    float*  out      = (float*)d_out;

    zero_kernel<<<128, 256, 0, stream>>>(hist);    // hist + tailcnt, ~3 us

    hist_kernel<<<TOTP / 256, 256, 0, stream>>>(pred, target, pts, cellids, hist);
    scan_kernel<<<4, 1024, 0, stream>>>(hist, cs, next);
    scatter_kernel<<<TOTP / 256, 256, 0, stream>>>(pts, cellids, next, sorted);

    nnA_kernel<<<TOTP * 4 / 256, 256, 0, stream>>>(sorted, cs, dout, tailcnt, taillist);
    tail_kernel<<<512, 256, 0, stream>>>(sorted, cs, tailcnt, taillist, dout);

    reduceA_kernel<<<64, 256, 0, stream>>>(dout, partials);
    reduceB_kernel<<<1, 64, 0, stream>>>(partials, out);
}